// Round 8
// baseline (158.306 us; speedup 1.0000x reference)
//
#include <hip/hip_runtime.h>

typedef __attribute__((ext_vector_type(8))) short short8;   // 8 bf16 = 4 VGPRs
typedef __attribute__((ext_vector_type(4))) float floatx4;  // MFMA acc
typedef __attribute__((ext_vector_type(4))) float f4v;      // vector float4

static __device__ __forceinline__ unsigned short f2bf(float f) {
    unsigned int u = __float_as_uint(f);
    return (unsigned short)((u + 0x7FFFu + ((u >> 16) & 1u)) >> 16);   // RNE
}

// ---- prep: weight repack (1536) + cumsum (32). No x conversion: the fused
// conv stages x directly (f32->bf16 in registers). Weights fragment-linear
// [12][4][8][512]: a conv wave's B-frag load is ONE contiguous 1KB load.
__global__ __launch_bounds__(256)
void prep_kernel(const int* __restrict__ target,
                 const float* __restrict__ w1, const float* __restrict__ w2,
                 ushort* __restrict__ w1q, ushort* __restrict__ w2q,
                 int* __restrict__ cumg)
{
    __shared__ int ps[256];
    const int blk = blockIdx.x, tid = threadIdx.x;
    if (blk < 1536) {
        const bool second = blk >= 768;
        const int e = (blk - (second ? 768 : 0)) * 256 + tid;
        const float* w = second ? w2 : w1;
        ushort* wq = second ? w2q : w1q;
        const int f = e / 768, j = e % 768;
        const int c = j & 255, kr = j >> 8;
        const int se = kr * 4 + (c >> 6);              // K-step 0..11
        const int kk = c & 63;
        const int wg = f >> 6, ni = (f >> 4) & 3, colf = f & 15;
        const int kh = kk >> 5, qk = (kk >> 3) & 3, jj = kk & 7;
        wq[(size_t)se * 16384 + wg * 4096 + (ni * 2 + kh) * 512
           + (qk * 16 + colf) * 8 + jj] = f2bf(w[f * 768 + c * 3 + kr]);
    } else {
        const int b = blk - 1536;
        const int v0 = target[b * 512 + 2 * tid];
        const int v1 = target[b * 512 + 2 * tid + 1];
        ps[tid] = v0 + v1;
        __syncthreads();
        for (int off = 1; off < 256; off <<= 1) {
            int t = (tid >= off) ? ps[tid - off] : 0;
            __syncthreads();
            ps[tid] += t;
            __syncthreads();
        }
        const int excl = tid ? ps[tid - 1] : 0;
        cumg[b * 512 + 2 * tid]     = excl + v0;
        cumg[b * 512 + 2 * tid + 1] = excl + v0 + v1;
    }
}

// ---- fused conv1+conv2 (+ interleaved gather) ----
// conv2's halo is +-1 row, so a 32-row output tile only needs h1 rows
// [t0-1,t0+33) -> computed in-block from x rows [t0-2,t0+34). h1 lives in
// LDS; NO h1b global round-trip, ONE conv kernel instead of two.
// Grid 1664 = 128 groups of 13: 4 conv + 9 gather (write-bound gather
// co-resident with latency-bound conv). LDS ~52KB -> 2 blocks/CU.
// Row-XOR swizzle (chunk ch at ch^(row&7), 16B chunks) on xs and hl so
// A-fragment ds_read_b128 (16 rows, same chunk) is bank-conflict-free.
__global__ __launch_bounds__(256, 2)
void fused_kernel(const float* __restrict__ x,       // [B][512][256] f32
                  const ushort* __restrict__ w1q,    // [12][4][8][512]
                  const ushort* __restrict__ w2q,
                  const float* __restrict__ c1b, const float* __restrict__ g1,
                  const float* __restrict__ b1,
                  const float* __restrict__ c2b, const float* __restrict__ g2,
                  const float* __restrict__ b2,
                  const float* __restrict__ lw, const float* __restrict__ lb,
                  const int* __restrict__ cumg,      // [B][512] cumsum
                  float* __restrict__ out0,          // [B][2304][256]
                  float* __restrict__ durp)          // [B][512]
{
    __shared__ union {
        struct {
            ushort xs[50 * 256];                     // 25KB x slab (bf16, swz)
            ushort hl[48 * 256];                     // 24KB h1 tile (bf16, swz)
            float sum_s[4][48], sq_s[4][48], mu_s[48], rs_s[48];
        } c;
        struct { int cum[512]; int sidx[64]; } g;
    } sh;

    const int tid = threadIdx.x;
    const int grp = blockIdx.x / 13, rmod = blockIdx.x % 13;

    if (rmod >= 4) {
        // ---------- gather: 64 output rows per block ----------
        const int bg = grp * 9 + (rmod - 4);         // [0,1152)
        const int b = bg / 36, t0o = (bg % 36) * 64;
        sh.g.cum[tid]       = cumg[b * 512 + tid];
        sh.g.cum[tid + 256] = cumg[b * 512 + 256 + tid];
        __syncthreads();
        const int total = sh.g.cum[511];
        if (tid < 64) {
            int t = t0o + tid;
            int lo = 0, hi = 512;
            while (lo < hi) {
                int mid = (lo + hi) >> 1;
                if (sh.g.cum[mid] <= t) lo = mid + 1; else hi = mid;
            }
            sh.g.sidx[tid] = (t < total) ? ((lo < 512) ? lo : 511) : -1;
        }
        __syncthreads();
        const f4v* x4 = (const f4v*)x;
        f4v* o4 = (f4v*)out0;
        const int lane6 = tid & 63, g4 = tid >> 6;
        #pragma unroll 4
        for (int rr = 0; rr < 16; ++rr) {
            int r = rr * 4 + g4;
            int idx = sh.g.sidx[r];
            f4v v = {0.f, 0.f, 0.f, 0.f};
            if (idx >= 0) v = x4[((size_t)(b * 512 + idx)) * 64 + lane6];
            __builtin_nontemporal_store(v, &o4[((size_t)(b * 2304 + t0o + r)) * 64 + lane6]);
        }
        return;
    }

    // ---------- fused conv path ----------
    const int conv_id = grp * 4 + rmod;              // [0,512)
    const int w_ = tid >> 6, lane = tid & 63;
    const int q = lane >> 4, col = lane & 15;
    const int b  = conv_id & 31;                     // XCD-affine batches
    const int t0 = (conv_id >> 5) << 5;
    const int rot = conv_id % 12;                    // K-step stagger

    // stage x rows [t0-2, t0+48) -> xs (bf16, row-XOR swizzled), zero-padded
    {
        const float* xb_ = x + (size_t)b * 512 * 256;
        #pragma unroll
        for (int r7 = 0; r7 < 7; ++r7) {
            const int id = r7 * 256 + tid;
            if (id < 1600) {                         // 50 rows x 32 chunks
                const int lr = id >> 5, ch = id & 31;
                const int xrow = t0 - 2 + lr;
                float4 v0 = make_float4(0.f, 0.f, 0.f, 0.f), v1 = v0;
                if (xrow >= 0 && xrow < 512) {
                    const float* px = xb_ + ((size_t)xrow * 256 + ch * 8);
                    v0 = *(const float4*)px;
                    v1 = *(const float4*)(px + 4);
                }
                short8 o;
                o[0] = f2bf(v0.x); o[1] = f2bf(v0.y); o[2] = f2bf(v0.z); o[3] = f2bf(v0.w);
                o[4] = f2bf(v1.x); o[5] = f2bf(v1.y); o[6] = f2bf(v1.z); o[7] = f2bf(v1.w);
                *(short8*)(sh.c.xs + lr * 256 + ((ch ^ (lr & 7)) << 3)) = o;
            }
        }
    }
    __syncthreads();

    // ---- conv1: 3 m-tiles (local h1 rows 0..47 = abs t rows t0-1..t0+46) ----
    floatx4 a1[3][4] = {};
    {
        const ushort* b1p = w1q + (size_t)w_ * 4096 + lane * 8;
        #pragma unroll
        for (int s = 0; s < 12; ++s) {
            int se = s + rot; if (se >= 12) se -= 12;
            const int kr = se >> 2, cb8 = (se & 3) << 3;
            short8 bf[4][2];
            #pragma unroll
            for (int ni = 0; ni < 4; ++ni)
                #pragma unroll
                for (int kh = 0; kh < 2; ++kh)
                    bf[ni][kh] = *(const short8*)(b1p + (size_t)se * 16384 + (ni * 2 + kh) * 512);
            #pragma unroll
            for (int mt = 0; mt < 3; ++mt) {
                short8 af[2];
                #pragma unroll
                for (int kh = 0; kh < 2; ++kh) {
                    const int xl = mt * 16 + col + kr;           // x slab row
                    const int ch = cb8 + kh * 4 + q;
                    af[kh] = *(const short8*)(sh.c.xs + xl * 256 + ((ch ^ (xl & 7)) << 3));
                }
                #pragma unroll
                for (int kh = 0; kh < 2; ++kh)
                    #pragma unroll
                    for (int ni = 0; ni < 4; ++ni)
                        a1[mt][ni] = __builtin_amdgcn_mfma_f32_16x16x32_bf16(
                            af[kh], bf[ni][kh], a1[mt][ni], 0, 0, 0);
            }
        }
    }

    // ---- LN1 over 48 rows + ReLU -> hl (masked to zero outside [0,512)) ----
    const int base_c = w_ * 64;
    {
        float cb4[4], gm4[4], bt4[4];
        #pragma unroll
        for (int ni = 0; ni < 4; ++ni) {
            cb4[ni] = c1b[base_c + ni * 16 + col];
            gm4[ni] = g1 [base_c + ni * 16 + col];
            bt4[ni] = b1 [base_c + ni * 16 + col];
        }
        float rsum[3][4] = {}, rsq[3][4] = {};
        #pragma unroll
        for (int mt = 0; mt < 3; ++mt)
            #pragma unroll
            for (int ni = 0; ni < 4; ++ni)
                #pragma unroll
                for (int r = 0; r < 4; ++r) {
                    float v = a1[mt][ni][r] + cb4[ni];
                    a1[mt][ni][r] = v;
                    rsum[mt][r] += v;
                    rsq [mt][r] += v * v;
                }
        #pragma unroll
        for (int mt = 0; mt < 3; ++mt)
            #pragma unroll
            for (int r = 0; r < 4; ++r) {
                float s = rsum[mt][r], ss = rsq[mt][r];
                #pragma unroll
                for (int d = 8; d > 0; d >>= 1) {
                    s  += __shfl_down(s,  d, 16);
                    ss += __shfl_down(ss, d, 16);
                }
                if (col == 0) {
                    sh.c.sum_s[w_][mt * 16 + q * 4 + r] = s;
                    sh.c.sq_s [w_][mt * 16 + q * 4 + r] = ss;
                }
            }
        __syncthreads();
        if (tid < 48) {
            float s  = sh.c.sum_s[0][tid] + sh.c.sum_s[1][tid] + sh.c.sum_s[2][tid] + sh.c.sum_s[3][tid];
            float ss = sh.c.sq_s [0][tid] + sh.c.sq_s [1][tid] + sh.c.sq_s [2][tid] + sh.c.sq_s [3][tid];
            float mu = s * (1.f / 256.f);
            sh.c.mu_s[tid] = mu;
            sh.c.rs_s[tid] = rsqrtf(ss * (1.f / 256.f) - mu * mu + 1e-5f);
        }
        __syncthreads();
        #pragma unroll
        for (int mt = 0; mt < 3; ++mt)
            #pragma unroll
            for (int ni = 0; ni < 4; ++ni)
                #pragma unroll
                for (int r = 0; r < 4; ++r) {
                    const int row = mt * 16 + q * 4 + r;         // local h1 row
                    const int tabs = t0 - 1 + row;               // abs seq row
                    float v = (a1[mt][ni][r] - sh.c.mu_s[row]) * sh.c.rs_s[row] * gm4[ni] + bt4[ni];
                    ushort u = (tabs >= 0 && tabs < 512) ? f2bf(fmaxf(v, 0.f)) : (ushort)0;
                    const int chunk = w_ * 8 + ni * 2 + (col >> 3);
                    sh.c.hl[row * 256 + (((chunk ^ (row & 7)) << 3) | (col & 7))] = u;
                }
    }
    __syncthreads();

    // ---- conv2: 2 m-tiles (out rows t0..t0+31), A from hl ----
    floatx4 a2[2][4] = {};
    {
        const ushort* b2p = w2q + (size_t)w_ * 4096 + lane * 8;
        #pragma unroll
        for (int s = 0; s < 12; ++s) {
            int se = s + rot; if (se >= 12) se -= 12;
            const int kr = se >> 2, cb8 = (se & 3) << 3;
            short8 bf[4][2];
            #pragma unroll
            for (int ni = 0; ni < 4; ++ni)
                #pragma unroll
                for (int kh = 0; kh < 2; ++kh)
                    bf[ni][kh] = *(const short8*)(b2p + (size_t)se * 16384 + (ni * 2 + kh) * 512);
            #pragma unroll
            for (int mt = 0; mt < 2; ++mt) {
                short8 af[2];
                #pragma unroll
                for (int kh = 0; kh < 2; ++kh) {
                    const int h2 = mt * 16 + col + kr;           // hl row
                    const int ch = cb8 + kh * 4 + q;
                    af[kh] = *(const short8*)(sh.c.hl + h2 * 256 + ((ch ^ (h2 & 7)) << 3));
                }
                #pragma unroll
                for (int kh = 0; kh < 2; ++kh)
                    #pragma unroll
                    for (int ni = 0; ni < 4; ++ni)
                        a2[mt][ni] = __builtin_amdgcn_mfma_f32_16x16x32_bf16(
                            af[kh], bf[ni][kh], a2[mt][ni], 0, 0, 0);
            }
        }
    }

    // ---- LN2 + ReLU + linear -> durp[t0..t0+32) ----
    {
        float cb4[4], gm4[4], bt4[4], lw4[4];
        #pragma unroll
        for (int ni = 0; ni < 4; ++ni) {
            cb4[ni] = c2b[base_c + ni * 16 + col];
            gm4[ni] = g2 [base_c + ni * 16 + col];
            bt4[ni] = b2 [base_c + ni * 16 + col];
            lw4[ni] = lw [base_c + ni * 16 + col];
        }
        float rsum[2][4] = {}, rsq[2][4] = {};
        #pragma unroll
        for (int mt = 0; mt < 2; ++mt)
            #pragma unroll
            for (int ni = 0; ni < 4; ++ni)
                #pragma unroll
                for (int r = 0; r < 4; ++r) {
                    float v = a2[mt][ni][r] + cb4[ni];
                    a2[mt][ni][r] = v;
                    rsum[mt][r] += v;
                    rsq [mt][r] += v * v;
                }
        #pragma unroll
        for (int mt = 0; mt < 2; ++mt)
            #pragma unroll
            for (int r = 0; r < 4; ++r) {
                float s = rsum[mt][r], ss = rsq[mt][r];
                #pragma unroll
                for (int d = 8; d > 0; d >>= 1) {
                    s  += __shfl_down(s,  d, 16);
                    ss += __shfl_down(ss, d, 16);
                }
                if (col == 0) {
                    sh.c.sum_s[w_][mt * 16 + q * 4 + r] = s;
                    sh.c.sq_s [w_][mt * 16 + q * 4 + r] = ss;
                }
            }
        __syncthreads();
        if (tid < 32) {
            float s  = sh.c.sum_s[0][tid] + sh.c.sum_s[1][tid] + sh.c.sum_s[2][tid] + sh.c.sum_s[3][tid];
            float ss = sh.c.sq_s [0][tid] + sh.c.sq_s [1][tid] + sh.c.sq_s [2][tid] + sh.c.sq_s [3][tid];
            float mu = s * (1.f / 256.f);
            sh.c.mu_s[tid] = mu;
            sh.c.rs_s[tid] = rsqrtf(ss * (1.f / 256.f) - mu * mu + 1e-5f);
        }
        __syncthreads();
        float dsum[2][4] = {};
        #pragma unroll
        for (int mt = 0; mt < 2; ++mt)
            #pragma unroll
            for (int ni = 0; ni < 4; ++ni)
                #pragma unroll
                for (int r = 0; r < 4; ++r) {
                    const int row = mt * 16 + q * 4 + r;
                    float v = (a2[mt][ni][r] - sh.c.mu_s[row]) * sh.c.rs_s[row] * gm4[ni] + bt4[ni];
                    dsum[mt][r] += fmaxf(v, 0.f) * lw4[ni];
                }
        #pragma unroll
        for (int mt = 0; mt < 2; ++mt)
            #pragma unroll
            for (int r = 0; r < 4; ++r) {
                float s = dsum[mt][r];
                #pragma unroll
                for (int d = 8; d > 0; d >>= 1) s += __shfl_down(s, d, 16);
                if (col == 0) sh.c.sum_s[w_][mt * 16 + q * 4 + r] = s;
            }
        __syncthreads();
        if (tid < 32)
            durp[b * 512 + t0 + tid] = fmaxf(sh.c.sum_s[0][tid] + sh.c.sum_s[1][tid]
                                           + sh.c.sum_s[2][tid] + sh.c.sum_s[3][tid] + lb[0], 0.f);
    }
}

extern "C" void kernel_launch(void* const* d_in, const int* in_sizes, int n_in,
                              void* d_out, int out_size, void* d_ws, size_t ws_size,
                              hipStream_t stream) {
    const float* x      = (const float*)d_in[0];
    const int*   target = (const int*)  d_in[1];
    const float* c1w = (const float*)d_in[3];
    const float* c1b = (const float*)d_in[4];
    const float* g1  = (const float*)d_in[5];
    const float* b1  = (const float*)d_in[6];
    const float* c2w = (const float*)d_in[7];
    const float* c2b = (const float*)d_in[8];
    const float* g2  = (const float*)d_in[9];
    const float* b2  = (const float*)d_in[10];
    const float* lw  = (const float*)d_in[11];
    const float* lb  = (const float*)d_in[12];

    ushort* w1q  = (ushort*)d_ws;                 // [12][4][8][512]
    ushort* w2q  = w1q + 196608;
    int*    cumg = (int*)(w2q + 196608);          // [32][512]

    float* out0 = (float*)d_out;                  // [32, 2304, 256]
    float* durp = out0 + (size_t)32 * 2304 * 256; // [32, 512]

    prep_kernel<<<1568, 256, 0, stream>>>(target, c1w, c2w, w1q, w2q, cumg);
    fused_kernel<<<1664, 256, 0, stream>>>(
        x, w1q, w2q, c1b, g1, b1, c2b, g2, b2, lw, lb, cumg, out0, durp);
}